// Round 23
// baseline (115.858 us; speedup 1.0000x reference)
//
#include <hip/hip_runtime.h>
#include <stdint.h>

// Problem constants (fixed by the reference)
constexpr int BB = 8;
constexpr int LL = 4096;
constexpr int DD = 128;
constexpr int KC = 1024;
constexpr int NN = BB * LL;          // 32768
constexpr int ZTOT = BB * DD * LL;   // 4194304

#define THREEFRY_PARTITIONABLE 1

typedef float f32x16 __attribute__((ext_vector_type(16)));
typedef short s16x8 __attribute__((ext_vector_type(8)));

union F4S8 { float4 f; s16x8 s; };

__device__ __forceinline__ ushort f2bf(float x) {   // RNE float->bf16
  uint32_t u = __float_as_uint(x);
  uint32_t r = u + 0x7FFFu + ((u >> 16) & 1u);
  return (ushort)(r >> 16);
}
__device__ __forceinline__ float bf2f(ushort h) {
  return __uint_as_float(((uint32_t)h) << 16);
}

__device__ __forceinline__ uint32_t rotl32(uint32_t x, int r) {
  return (x << r) | (x >> (32 - r));
}

__device__ __forceinline__ void threefry2x32(uint32_t k0, uint32_t k1,
                                             uint32_t x0, uint32_t x1,
                                             uint32_t* o0, uint32_t* o1) {
  uint32_t ks0 = k0, ks1 = k1, ks2 = 0x1BD11BDAu ^ k0 ^ k1;
  x0 += ks0; x1 += ks1;
  x0 += x1; x1 = rotl32(x1, 13); x1 ^= x0;
  x0 += x1; x1 = rotl32(x1, 15); x1 ^= x0;
  x0 += x1; x1 = rotl32(x1, 26); x1 ^= x0;
  x0 += x1; x1 = rotl32(x1, 6);  x1 ^= x0;
  x0 += ks1; x1 += ks2 + 1u;
  x0 += x1; x1 = rotl32(x1, 17); x1 ^= x0;
  x0 += x1; x1 = rotl32(x1, 29); x1 ^= x0;
  x0 += x1; x1 = rotl32(x1, 16); x1 ^= x0;
  x0 += x1; x1 = rotl32(x1, 24); x1 ^= x0;
  x0 += ks2; x1 += ks0 + 2u;
  x0 += x1; x1 = rotl32(x1, 13); x1 ^= x0;
  x0 += x1; x1 = rotl32(x1, 15); x1 ^= x0;
  x0 += x1; x1 = rotl32(x1, 26); x1 ^= x0;
  x0 += x1; x1 = rotl32(x1, 6);  x1 ^= x0;
  x0 += ks0; x1 += ks1 + 3u;
  x0 += x1; x1 = rotl32(x1, 17); x1 ^= x0;
  x0 += x1; x1 = rotl32(x1, 29); x1 ^= x0;
  x0 += x1; x1 = rotl32(x1, 16); x1 ^= x0;
  x0 += x1; x1 = rotl32(x1, 24); x1 ^= x0;
  x0 += ks1; x1 += ks2 + 4u;
  x0 += x1; x1 = rotl32(x1, 13); x1 ^= x0;
  x0 += x1; x1 = rotl32(x1, 15); x1 ^= x0;
  x0 += x1; x1 = rotl32(x1, 26); x1 ^= x0;
  x0 += x1; x1 = rotl32(x1, 6);  x1 ^= x0;
  x0 += ks2; x1 += ks0 + 5u;
  *o0 = x0; *o1 = x1;
}

// Kernel 0: e_sq per code, bf16-split E fragments (MFMA A-layout linear),
// lacc + done-counter init.
__global__ __launch_bounds__(128) void k_prep(const float* __restrict__ E,
                                              float* __restrict__ esq,
                                              double* __restrict__ lacc,
                                              ushort* __restrict__ E0f,
                                              ushort* __restrict__ E1f,
                                              int* __restrict__ done) {
  const int k = blockIdx.x;       // code
  const int d = threadIdx.x;      // dim
  float v = E[k * DD + d];
  __shared__ float r[128];
  __shared__ ushort sh0[128], sh1[128];
  ushort h0 = f2bf(v);
  float v0 = bf2f(h0);
  ushort h1 = f2bf(v - v0);
  sh0[d] = h0; sh1[d] = h1;
  r[d] = v * v;
  __syncthreads();
  for (int s = 64; s > 0; s >>= 1) {
    if (d < s) r[d] += r[d + s];
    __syncthreads();
  }
  if (d == 0) {
    esq[k] = r[0];
    if (k == 0) { lacc[0] = 0.0; done[0] = 0; }
  }
  if (d < 32) {
    const ushort* src = (d < 16) ? sh0 : sh1;
    ushort* dst = (d < 16) ? E0f : E1f;
    int p = d & 15, h = p & 1, ks = p >> 1;
    int slot = ((k >> 5) * 8 + ks) * 64 + (k & 31) + 32 * h;
    int off = ks * 16 + h * 8;
    uint32_t w0 = (uint32_t)src[off + 0] | ((uint32_t)src[off + 1] << 16);
    uint32_t w1 = (uint32_t)src[off + 2] | ((uint32_t)src[off + 3] << 16);
    uint32_t w2 = (uint32_t)src[off + 4] | ((uint32_t)src[off + 5] << 16);
    uint32_t w3 = (uint32_t)src[off + 6] | ((uint32_t)src[off + 7] << 16);
    uint4 val; val.x = w0; val.y = w1; val.z = w2; val.w = w3;
    *(uint4*)(dst + (size_t)slot * 8) = val;
  }
}

// Kernel 1 (r12/r16-proven champion): MFMA distance argmin, 4-way code-split.
__global__ __launch_bounds__(256) void k_dist(const float* __restrict__ Z,
                                              const float* __restrict__ E,
                                              const ushort* __restrict__ E0f,
                                              const ushort* __restrict__ E1f,
                                              const float* __restrict__ esq,
                                              int* __restrict__ idx_out,
                                              float* __restrict__ zflat) {
  __shared__ float Zt[128][33];    // [dim][row], pad 33: frag reads conflict-free
  __shared__ float esh[1024];      // 4 KB
  __shared__ float mv1[4][32], mv2[4][32];
  __shared__ int   mi1[4][32], mi2[4][32];

  const int tid = threadIdx.x;
  const int w = tid >> 6;          // wave id = code-split id
  const int lane = tid & 63;
  const int hi = lane >> 5;
  const int rr = lane & 31;
  const int r0 = blockIdx.x * 32;
  const int b = r0 >> 12;
  const int l0 = r0 & (LL - 1);

  // stage Z tile (32 rows): per dim, 128B contiguous
  const float* zsrc = Z + (size_t)b * DD * LL + l0;
#pragma unroll
  for (int p = 0; p < 4; ++p) {
    int f = p * 256 + tid;
    int d = f >> 3;
    int g = f & 7;
    float4 v = *(const float4*)(zsrc + (size_t)d * LL + g * 4);
    Zt[d][g * 4 + 0] = v.x;
    Zt[d][g * 4 + 1] = v.y;
    Zt[d][g * 4 + 2] = v.z;
    Zt[d][g * 4 + 3] = v.w;
  }
  {  // stage esq
    float4 e4 = *(const float4*)(esq + tid * 4);
    *(float4*)(&esh[tid * 4]) = e4;
  }
  __syncthreads();

  // fused zflat write: rows r0..r0+31 in (N,D) row-major
  {
    float* dst = zflat + (size_t)r0 * DD;
#pragma unroll
    for (int p = 0; p < 4; ++p) {
      int f = p * 256 + tid;
      int row = f >> 5;
      int dq = f & 31;
      float4 v;
      v.x = Zt[dq * 4 + 0][row];
      v.y = Zt[dq * 4 + 1][row];
      v.z = Zt[dq * 4 + 2][row];
      v.w = Zt[dq * 4 + 3][row];
      *(float4*)(dst + (size_t)row * DD + dq * 4) = v;
    }
  }

  // build B-frags (z bf16 splits): lane holds row rr, dims ks*16+hi*8+j
  s16x8 B0[8], B1[8];
#pragma unroll
  for (int ks = 0; ks < 8; ++ks) {
    s16x8 b0, b1;
#pragma unroll
    for (int j = 0; j < 8; ++j) {
      float z = Zt[ks * 16 + hi * 8 + j][rr];
      ushort h0 = f2bf(z);
      float z0f = bf2f(h0);
      ushort h1 = f2bf(z - z0f);
      b0[j] = (short)h0;
      b1[j] = (short)h1;
    }
    B0[ks] = b0; B1[ks] = b1;
  }

  // wave scans its 8 code-subtiles (codes w*256 .. w*256+255, ascending)
  float b1v = 3.4e38f, b2v = 3.4e38f;
  int b1i = 0, b2i = 0;
  const float4* e0p = (const float4*)E0f;
  const float4* e1p = (const float4*)E1f;

  for (int s = 0; s < 8; ++s) {
    const int sg = w * 8 + s;        // global subtile
    f32x16 acc;
#pragma unroll
    for (int i = 0; i < 16; ++i) acc[i] = 0.0f;
    const int base = sg * 512 + lane;
#pragma unroll
    for (int ks = 0; ks < 8; ++ks) {
      F4S8 ua, ub;
      ua.f = e0p[base + ks * 64];
      ub.f = e1p[base + ks * 64];
      acc = __builtin_amdgcn_mfma_f32_32x32x16_bf16(ua.s, B0[ks], acc, 0, 0, 0);
      acc = __builtin_amdgcn_mfma_f32_32x32x16_bf16(ua.s, B1[ks], acc, 0, 0, 0);
      acc = __builtin_amdgcn_mfma_f32_32x32x16_bf16(ub.s, B0[ks], acc, 0, 0, 0);
    }
    // finalize: lane-local codes, ascending -> first-index tie-break
#pragma unroll
    for (int reg = 0; reg < 16; ++reg) {
      int cl = (reg & 3) + 8 * (reg >> 2) + 4 * hi;
      int c = sg * 32 + cl;
      float rv = fmaf(-2.0f, acc[reg], esh[c]);   // zsq-free ranking key
      if (rv < b1v) { b2v = b1v; b2i = b1i; b1v = rv; b1i = c; }
      else if (rv < b2v) { b2v = rv; b2i = c; }
    }
  }

  // merge the two half-lanes (codes interleave -> lexicographic (val, idx))
  float ov1 = __shfl_xor(b1v, 32, 64); int oi1 = __shfl_xor(b1i, 32, 64);
  float ov2 = __shfl_xor(b2v, 32, 64); int oi2 = __shfl_xor(b2i, 32, 64);
  if (ov1 < b1v || (ov1 == b1v && oi1 < b1i)) { b2v = b1v; b2i = b1i; b1v = ov1; b1i = oi1; }
  else if (ov1 < b2v || (ov1 == b2v && oi1 < b2i)) { b2v = ov1; b2i = oi1; }
  if (ov2 < b2v || (ov2 == b2v && oi2 < b2i)) { b2v = ov2; b2i = oi2; }

  if (hi == 0) {
    mv1[w][rr] = b1v; mi1[w][rr] = b1i;
    mv2[w][rr] = b2v; mi2[w][rr] = b2i;
  }
  __syncthreads();

  // final merge across 4 waves + selective exact refine, one thread per row
  if (tid < 32) {
    const int row = tid;
    float fb1 = mv1[0][row]; int fi1 = mi1[0][row];
    float fb2 = mv2[0][row]; int fi2 = mi2[0][row];
#pragma unroll
    for (int q = 1; q < 4; ++q) {
      float v1 = mv1[q][row]; int i1 = mi1[q][row];
      float v2 = mv2[q][row]; int i2 = mi2[q][row];
      if (v1 < fb1 || (v1 == fb1 && i1 < fi1)) {
        fb2 = fb1; fi2 = fi1; fb1 = v1; fi1 = i1;
      } else if (v1 < fb2 || (v1 == fb2 && i1 < fi2)) {
        fb2 = v1; fi2 = i1;
      }
      if (v2 < fb2 || (v2 == fb2 && i2 < fi2)) { fb2 = v2; fi2 = i2; }
    }

    int fi = fi1;
    if (fb2 - fb1 <= 4e-5f) {
      float zsq = 0.0f;
#pragma unroll 4
      for (int d = 0; d < 128; ++d) {
        float z = Zt[d][row];
        zsq = fmaf(z, z, zsq);
      }
      float dot1 = 0.0f, dot2 = 0.0f;
      const float* e1r = E + (size_t)fi1 * DD;
      const float* e2r = E + (size_t)fi2 * DD;
      for (int d = 0; d < 128; ++d) {
        float z = Zt[d][row];
        dot1 = fmaf(z, e1r[d], dot1);
        dot2 = fmaf(z, e2r[d], dot2);
      }
      float k1 = (zsq + esh[fi1]) - 2.0f * dot1;
      float k2 = (zsq + esh[fi2]) - 2.0f * dot2;
      if (k2 < k1 || (k2 == k1 && fi2 < fi1)) fi = fi2;
    }
    idx_out[r0 + row] = fi;
  }
}

// Counting-sort phase 1: per-block histogram of 1024 indices (LDS-local atomics).
__global__ __launch_bounds__(1024) void k_hist(const int* __restrict__ idxs,
                                               int* __restrict__ part_cnt) {
  __shared__ int h[1024];
  const int tid = threadIdx.x;
  const int j = blockIdx.x;      // 32 blocks
  h[tid] = 0;
  __syncthreads();
  int k = idxs[j * 1024 + tid];
  atomicAdd(&h[k], 1);
  __syncthreads();
  part_cnt[j * 1024 + tid] = h[tid];
}

// Counting-sort phase 2 + cluster EMA fused. Wave-shuffle prefix (3 barriers).
__global__ __launch_bounds__(1024) void k_scan(int* __restrict__ part_cnt,
                                               int* __restrict__ code_start,
                                               int* __restrict__ icnt,
                                               float* __restrict__ counts,
                                               const float* __restrict__ cs_in,
                                               float* __restrict__ smooth,
                                               int* __restrict__ ridx,
                                               int* __restrict__ deadf) {
  const int k = threadIdx.x;
  const int lane = k & 63;
  const int wv = k >> 6;         // 16 waves
  int base[32];
  int s = 0;
#pragma unroll
  for (int j = 0; j < 32; ++j) {
    base[j] = s;
    s += part_cnt[j * 1024 + k];
  }
  icnt[k] = s;
  counts[k] = (float)s;

  // inclusive prefix within wave via shfl_up
  int ps = s;
#pragma unroll
  for (int off = 1; off < 64; off <<= 1) {
    int v = __shfl_up(ps, off, 64);
    if (lane >= off) ps += v;
  }
  __shared__ int wtot[16];
  if (lane == 63) wtot[wv] = ps;
  __syncthreads();
  if (k < 16) {
    int v = wtot[k];
#pragma unroll
    for (int off = 1; off < 16; off <<= 1) {
      int u = __shfl_up(v, off, 64);
      if (lane >= off) v += u;
    }
    wtot[k] = v;   // inclusive wave totals prefix
  }
  __syncthreads();
  int wbase = (wv > 0) ? wtot[wv - 1] : 0;
  int excl = (ps + wbase) - s;
  code_start[k] = excl;
#pragma unroll
  for (int j = 0; j < 32; ++j) {
    part_cnt[j * 1024 + k] = excl + base[j];   // becomes part_base
  }

  // ---- fused cluster EMA (was k_cluster) ----
  float c = (float)s;
  float t1 = 0.99f * cs_in[k];
  float t2 = 0.01f * c;
  float nc = t1 + t2;
  bool dead = nc < 0.5f;

  uint32_t bits;
#if THREEFRY_PARTITIONABLE
  {
    uint32_t o0, o1;
    threefry2x32(0u, 42u, 0u, (uint32_t)k, &o0, &o1);
    bits = o0 ^ o1;
  }
#else
  {
    uint32_t o0, o1;
    if (k < 512) { threefry2x32(0u, 42u, (uint32_t)k, (uint32_t)(k + 512), &o0, &o1); bits = o0; }
    else         { threefry2x32(0u, 42u, (uint32_t)(k - 512), (uint32_t)k, &o0, &o1); bits = o1; }
  }
#endif
  int r = (int)(bits & 0x7FFFu);

  float rep = dead ? 0.5f : nc;

  // block-wide sum of rep: wave butterfly + 16 partials + broadcast
  float fs = rep;
#pragma unroll
  for (int off = 32; off > 0; off >>= 1) fs += __shfl_xor(fs, off, 64);
  __shared__ float ftot[16];
  __shared__ float nsh;
  if (lane == 0) ftot[wv] = fs;
  __syncthreads();
  if (k == 0) {
    float n = 0.0f;
#pragma unroll
    for (int i = 0; i < 16; ++i) n += ftot[i];
    nsh = n;
  }
  __syncthreads();
  float n = nsh;

  float sm = ((rep + 1e-5f) / (n + 0.01024f)) * n;
  smooth[k] = sm;
  ridx[k] = r;
  deadf[k] = dead ? 1 : 0;
}

// Counting-sort phase 3: scatter row ids (LDS cursor seeded from part_base).
__global__ __launch_bounds__(1024) void k_scatter(const int* __restrict__ idxs,
                                                  const int* __restrict__ part_base,
                                                  int* __restrict__ rowlist) {
  __shared__ int cur[1024];
  const int tid = threadIdx.x;
  const int j = blockIdx.x;      // 32 blocks
  cur[tid] = part_base[j * 1024 + tid];
  __syncthreads();
  int row = j * 1024 + tid;
  int k = idxs[row];
  int pos = atomicAdd(&cur[k], 1);
  rowlist[pos] = row;
}

// Gather segment sum via rowlist + fused k_emb — 8 rows in flight per block.
__global__ __launch_bounds__(256) void k_wsum2(const float* __restrict__ zflat,
                                               const int* __restrict__ rowlist,
                                               const int* __restrict__ code_start,
                                               const int* __restrict__ icnt,
                                               const float* __restrict__ avg_in,
                                               const float* __restrict__ smooth,
                                               const int* __restrict__ ridx,
                                               const int* __restrict__ deadf,
                                               float* __restrict__ nemb) {
  const int k = blockIdx.x;
  const int tid = threadIdx.x;
  const int g = tid >> 5;        // row-group 0..7
  const int ln = tid & 31;       // lane -> dims ln*4 .. ln*4+3
  __shared__ float red[8][128];

  const int start = code_start[k];
  const int m = icnt[k];
  float a0 = 0.f, a1 = 0.f, a2 = 0.f, a3 = 0.f;
  for (int j = g; j < m; j += 8) {
    int row = rowlist[start + j];
    const float4 v = *(const float4*)(zflat + (size_t)row * DD + ln * 4);
    a0 += v.x; a1 += v.y; a2 += v.z; a3 += v.w;
  }
  red[g][ln * 4 + 0] = a0;
  red[g][ln * 4 + 1] = a1;
  red[g][ln * 4 + 2] = a2;
  red[g][ln * 4 + 3] = a3;
  __syncthreads();
#pragma unroll
  for (int s = 4; s >= 1; s >>= 1) {
    if (g < s) {
      red[g][ln * 4 + 0] += red[g + s][ln * 4 + 0];
      red[g][ln * 4 + 1] += red[g + s][ln * 4 + 1];
      red[g][ln * 4 + 2] += red[g + s][ln * 4 + 2];
      red[g][ln * 4 + 3] += red[g + s][ln * 4 + 3];
    }
    __syncthreads();
  }
  if (g == 0) {
    const int dd = ln * 4;
    float4 av = *(const float4*)(avg_in + (size_t)k * DD + dd);
    float sm = smooth[k];
    float na0 = 0.99f * av.x + 0.01f * red[0][dd + 0];
    float na1 = 0.99f * av.y + 0.01f * red[0][dd + 1];
    float na2 = 0.99f * av.z + 0.01f * red[0][dd + 2];
    float na3 = 0.99f * av.w + 0.01f * red[0][dd + 3];
    if (deadf[k]) {
      int r = ridx[k];
      const float4 zv = *(const float4*)(zflat + (size_t)r * DD + dd);
      na0 = zv.x * 0.5f;   // rvec * RESTART_THRESHOLD
      na1 = zv.y * 0.5f;
      na2 = zv.z * 0.5f;
      na3 = zv.w * 0.5f;
    }
    float4 o;
    o.x = na0 / sm; o.y = na1 / sm; o.z = na2 / sm; o.w = na3 / sm;
    *(float4*)(nemb + (size_t)k * DD + dd) = o;
  }
}

// Kernel 4: tile-structured gather/output + fused loss finalize (last block).
__global__ __launch_bounds__(256) void k_out(const float* __restrict__ Z,
                                             const float* __restrict__ nemb,
                                             const int* __restrict__ idxs,
                                             float* __restrict__ out,
                                             double* __restrict__ lacc,
                                             int* __restrict__ done) {
  __shared__ float Zt[128][33];   // [d][row]
  __shared__ float Ot[128][33];   // [d][row] output staged
  __shared__ int sidx[32];
  __shared__ float lred[4];

  const int tid = threadIdx.x;
  const int r0 = blockIdx.x * 32;
  const int b = r0 >> 12;
  const int l0 = r0 & (LL - 1);

  // stage Z tile coalesced (128B contiguous per d)
  const float* zsrc = Z + (size_t)b * DD * LL + l0;
#pragma unroll
  for (int p = 0; p < 4; ++p) {
    int f = p * 256 + tid;
    int d = f >> 3;
    int g = f & 7;
    float4 v = *(const float4*)(zsrc + (size_t)d * LL + g * 4);
    Zt[d][g * 4 + 0] = v.x;
    Zt[d][g * 4 + 1] = v.y;
    Zt[d][g * 4 + 2] = v.z;
    Zt[d][g * 4 + 3] = v.w;
  }
  if (tid < 32) sidx[tid] = idxs[r0 + tid];
  __syncthreads();

  // each 32-lane group handles one row per iter: coalesced 512B nemb row reads
  const int grp = tid >> 5;   // 0..7
  const int ln = tid & 31;
  float lsum = 0.0f;
#pragma unroll
  for (int it = 0; it < 4; ++it) {
    int row = it * 8 + grp;
    int fi = sidx[row];
    float4 q4 = *(const float4*)(nemb + (size_t)fi * DD + ln * 4);
    float z0 = Zt[ln * 4 + 0][row];
    float z1 = Zt[ln * 4 + 1][row];
    float z2 = Zt[ln * 4 + 2][row];
    float z3 = Zt[ln * 4 + 3][row];
    float o0 = z0 + (q4.x - z0);   // reference expr tree: z_e + (z_q - z_e)
    float o1 = z1 + (q4.y - z1);
    float o2 = z2 + (q4.z - z2);
    float o3 = z3 + (q4.w - z3);
    Ot[ln * 4 + 0][row] = o0;
    Ot[ln * 4 + 1][row] = o1;
    Ot[ln * 4 + 2][row] = o2;
    Ot[ln * 4 + 3][row] = o3;
    float d0 = z0 - q4.x, d1 = z1 - q4.y, d2 = z2 - q4.z, d3 = z3 - q4.w;
    lsum += d0 * d0 + d1 * d1 + d2 * d2 + d3 * d3;
  }
  __syncthreads();

  // write z_q_st coalesced (128B contiguous per d)
  float* dstz = out + (size_t)b * DD * LL + l0;
#pragma unroll
  for (int p = 0; p < 4; ++p) {
    int f = p * 256 + tid;
    int d = f >> 3;
    int g = f & 7;
    float4 v;
    v.x = Ot[d][g * 4 + 0];
    v.y = Ot[d][g * 4 + 1];
    v.z = Ot[d][g * 4 + 2];
    v.w = Ot[d][g * 4 + 3];
    *(float4*)(dstz + (size_t)d * LL + g * 4) = v;
  }
  // indices_map as floats
  if (tid < 32) out[(size_t)ZTOT + r0 + tid] = (float)sidx[tid];

  // loss partial: wave reduce then one double atomic per block; the block that
  // finishes last (fence+counter) computes the final scalars (replaces k_fin).
  for (int off = 32; off > 0; off >>= 1) lsum += __shfl_down(lsum, off, 64);
  if ((tid & 63) == 0) lred[tid >> 6] = lsum;
  __syncthreads();
  if (tid == 0) {
    float tot = (lred[0] + lred[1]) + (lred[2] + lred[3]);
    atomicAdd(lacc, (double)tot);
    __threadfence();                       // lacc update visible before count
    int prev = atomicAdd(done, 1);
    if (prev == (int)(NN / 32) - 1) {      // last block to finish
      __threadfence();                     // all lacc adds visible
      double S = atomicAdd(lacc, 0.0);     // atomic read of final sum
      float cb = (float)(S / (double)ZTOT);
      float bc = 0.25f * cb;
      float vq = cb + bc;
      float* o = out + (size_t)ZTOT + NN;
      o[0] = vq;
      o[1] = cb;
      o[2] = bc;
    }
  }
}

extern "C" void kernel_launch(void* const* d_in, const int* in_sizes, int n_in,
                              void* d_out, int out_size, void* d_ws, size_t ws_size,
                              hipStream_t stream) {
  const float* Z  = (const float*)d_in[0];   // z_e        (8,128,4096)
  const float* E  = (const float*)d_in[1];   // embedding  (1024,128)
  const float* CS = (const float*)d_in[2];   // cluster_size (1024,)
  const float* EA = (const float*)d_in[3];   // embedding_avg (1024,128)
  float* out = (float*)d_out;
  float* ws = (float*)d_ws;

  float* counts = ws;                        // 1024
  float* esq    = ws + 1024;                 // 1024
  float* smooth = ws + 2048;                 // 1024
  int*   ridx   = (int*)(ws + 3072);         // 1024
  int*   deadf  = (int*)(ws + 4096);         // 1024
  float* nemb   = ws + 8192 + 131072;        // 131072 floats (512 KB)
  int*   idxs   = (int*)(ws + 270336);       // 32768
  double* lacc  = (double*)(ws + 303104);    // 8B aligned

  int* rowlist    = (int*)(ws + 303360);     // 32768 ints
  int* code_start = (int*)(ws + 336128);     // 1024 ints
  int* icnt       = (int*)(ws + 337152);     // 1024 ints
  int* done       = (int*)(ws + 338176);     // 1 int

  // bf16-split E fragment buffers reuse the nemb slot: consumed by k_dist;
  // part_cnt then reuses the same slot; k_wsum2 finally writes nemb.
  ushort* E0f = (ushort*)nemb;
  ushort* E1f = (ushort*)(nemb + 65536);
  int* part_cnt = (int*)nemb;

  // zflat (N,D) = 16.8 MB parked in d_out[0..ZTOT): written by k_dist (fused
  // transpose), consumed by k_wsum2, overwritten by k_out (stream-ordered).
  float* zflat = out;

  k_prep<<<KC, DD, 0, stream>>>(E, esq, lacc, E0f, E1f, done);
  k_dist<<<NN / 32, 256, 0, stream>>>(Z, E, E0f, E1f, esq, idxs, zflat);
  k_hist<<<32, 1024, 0, stream>>>(idxs, part_cnt);
  k_scan<<<1, 1024, 0, stream>>>(part_cnt, code_start, icnt, counts,
                                 CS, smooth, ridx, deadf);
  k_scatter<<<32, 1024, 0, stream>>>(idxs, part_cnt, rowlist);
  k_wsum2<<<KC, 256, 0, stream>>>(zflat, rowlist, code_start, icnt,
                                  EA, smooth, ridx, deadf, nemb);
  k_out<<<NN / 32, 256, 0, stream>>>(Z, nemb, idxs, out, lacc, done);
}

// Round 24
// 87.717 us; speedup vs baseline: 1.3208x; 1.3208x over previous
//
#include <hip/hip_runtime.h>
#include <stdint.h>

// Problem constants (fixed by the reference)
constexpr int BB = 8;
constexpr int LL = 4096;
constexpr int DD = 128;
constexpr int KC = 1024;
constexpr int NN = BB * LL;          // 32768
constexpr int ZTOT = BB * DD * LL;   // 4194304

#define THREEFRY_PARTITIONABLE 1

typedef float f32x16 __attribute__((ext_vector_type(16)));
typedef short s16x8 __attribute__((ext_vector_type(8)));

union F4S8 { float4 f; s16x8 s; };

__device__ __forceinline__ ushort f2bf(float x) {   // RNE float->bf16
  uint32_t u = __float_as_uint(x);
  uint32_t r = u + 0x7FFFu + ((u >> 16) & 1u);
  return (ushort)(r >> 16);
}
__device__ __forceinline__ float bf2f(ushort h) {
  return __uint_as_float(((uint32_t)h) << 16);
}

__device__ __forceinline__ uint32_t rotl32(uint32_t x, int r) {
  return (x << r) | (x >> (32 - r));
}

__device__ __forceinline__ void threefry2x32(uint32_t k0, uint32_t k1,
                                             uint32_t x0, uint32_t x1,
                                             uint32_t* o0, uint32_t* o1) {
  uint32_t ks0 = k0, ks1 = k1, ks2 = 0x1BD11BDAu ^ k0 ^ k1;
  x0 += ks0; x1 += ks1;
  x0 += x1; x1 = rotl32(x1, 13); x1 ^= x0;
  x0 += x1; x1 = rotl32(x1, 15); x1 ^= x0;
  x0 += x1; x1 = rotl32(x1, 26); x1 ^= x0;
  x0 += x1; x1 = rotl32(x1, 6);  x1 ^= x0;
  x0 += ks1; x1 += ks2 + 1u;
  x0 += x1; x1 = rotl32(x1, 17); x1 ^= x0;
  x0 += x1; x1 = rotl32(x1, 29); x1 ^= x0;
  x0 += x1; x1 = rotl32(x1, 16); x1 ^= x0;
  x0 += x1; x1 = rotl32(x1, 24); x1 ^= x0;
  x0 += ks2; x1 += ks0 + 2u;
  x0 += x1; x1 = rotl32(x1, 13); x1 ^= x0;
  x0 += x1; x1 = rotl32(x1, 15); x1 ^= x0;
  x0 += x1; x1 = rotl32(x1, 26); x1 ^= x0;
  x0 += x1; x1 = rotl32(x1, 6);  x1 ^= x0;
  x0 += ks0; x1 += ks1 + 3u;
  x0 += x1; x1 = rotl32(x1, 17); x1 ^= x0;
  x0 += x1; x1 = rotl32(x1, 29); x1 ^= x0;
  x0 += x1; x1 = rotl32(x1, 16); x1 ^= x0;
  x0 += x1; x1 = rotl32(x1, 24); x1 ^= x0;
  x0 += ks1; x1 += ks2 + 4u;
  x0 += x1; x1 = rotl32(x1, 13); x1 ^= x0;
  x0 += x1; x1 = rotl32(x1, 15); x1 ^= x0;
  x0 += x1; x1 = rotl32(x1, 26); x1 ^= x0;
  x0 += x1; x1 = rotl32(x1, 6);  x1 ^= x0;
  x0 += ks2; x1 += ks0 + 5u;
  *o0 = x0; *o1 = x1;
}

// Kernel 0: e_sq per code, bf16-split E fragments (MFMA A-layout linear), lacc init.
// Frag layout: slot = ((k>>5)*8 + ks)*64 + (k&31) + 32*h ; 8 bf16 = dims ks*16+h*8+j.
__global__ __launch_bounds__(128) void k_prep(const float* __restrict__ E,
                                              float* __restrict__ esq,
                                              double* __restrict__ lacc,
                                              ushort* __restrict__ E0f,
                                              ushort* __restrict__ E1f) {
  const int k = blockIdx.x;       // code
  const int d = threadIdx.x;      // dim
  float v = E[k * DD + d];
  __shared__ float r[128];
  __shared__ ushort sh0[128], sh1[128];
  ushort h0 = f2bf(v);
  float v0 = bf2f(h0);
  ushort h1 = f2bf(v - v0);
  sh0[d] = h0; sh1[d] = h1;
  r[d] = v * v;
  __syncthreads();
  for (int s = 64; s > 0; s >>= 1) {
    if (d < s) r[d] += r[d + s];
    __syncthreads();
  }
  if (d == 0) {
    esq[k] = r[0];
    if (k == 0) lacc[0] = 0.0;
  }
  if (d < 32) {
    const ushort* src = (d < 16) ? sh0 : sh1;
    ushort* dst = (d < 16) ? E0f : E1f;
    int p = d & 15, h = p & 1, ks = p >> 1;
    int slot = ((k >> 5) * 8 + ks) * 64 + (k & 31) + 32 * h;
    int off = ks * 16 + h * 8;
    uint32_t w0 = (uint32_t)src[off + 0] | ((uint32_t)src[off + 1] << 16);
    uint32_t w1 = (uint32_t)src[off + 2] | ((uint32_t)src[off + 3] << 16);
    uint32_t w2 = (uint32_t)src[off + 4] | ((uint32_t)src[off + 5] << 16);
    uint32_t w3 = (uint32_t)src[off + 6] | ((uint32_t)src[off + 7] << 16);
    uint4 val; val.x = w0; val.y = w1; val.z = w2; val.w = w3;
    *(uint4*)(dst + (size_t)slot * 8) = val;
  }
}

// Kernel 1 (r12/r16-proven champion): MFMA distance argmin, 4-way code-split.
__global__ __launch_bounds__(256) void k_dist(const float* __restrict__ Z,
                                              const float* __restrict__ E,
                                              const ushort* __restrict__ E0f,
                                              const ushort* __restrict__ E1f,
                                              const float* __restrict__ esq,
                                              int* __restrict__ idx_out,
                                              float* __restrict__ zflat) {
  __shared__ float Zt[128][33];    // [dim][row], pad 33: frag reads conflict-free
  __shared__ float esh[1024];      // 4 KB
  __shared__ float mv1[4][32], mv2[4][32];
  __shared__ int   mi1[4][32], mi2[4][32];

  const int tid = threadIdx.x;
  const int w = tid >> 6;          // wave id = code-split id
  const int lane = tid & 63;
  const int hi = lane >> 5;
  const int rr = lane & 31;
  const int r0 = blockIdx.x * 32;
  const int b = r0 >> 12;
  const int l0 = r0 & (LL - 1);

  // stage Z tile (32 rows): per dim, 128B contiguous
  const float* zsrc = Z + (size_t)b * DD * LL + l0;
#pragma unroll
  for (int p = 0; p < 4; ++p) {
    int f = p * 256 + tid;
    int d = f >> 3;
    int g = f & 7;
    float4 v = *(const float4*)(zsrc + (size_t)d * LL + g * 4);
    Zt[d][g * 4 + 0] = v.x;
    Zt[d][g * 4 + 1] = v.y;
    Zt[d][g * 4 + 2] = v.z;
    Zt[d][g * 4 + 3] = v.w;
  }
  {  // stage esq
    float4 e4 = *(const float4*)(esq + tid * 4);
    *(float4*)(&esh[tid * 4]) = e4;
  }
  __syncthreads();

  // fused zflat write: rows r0..r0+31 in (N,D) row-major
  {
    float* dst = zflat + (size_t)r0 * DD;
#pragma unroll
    for (int p = 0; p < 4; ++p) {
      int f = p * 256 + tid;
      int row = f >> 5;
      int dq = f & 31;
      float4 v;
      v.x = Zt[dq * 4 + 0][row];
      v.y = Zt[dq * 4 + 1][row];
      v.z = Zt[dq * 4 + 2][row];
      v.w = Zt[dq * 4 + 3][row];
      *(float4*)(dst + (size_t)row * DD + dq * 4) = v;
    }
  }

  // build B-frags (z bf16 splits): lane holds row rr, dims ks*16+hi*8+j
  s16x8 B0[8], B1[8];
#pragma unroll
  for (int ks = 0; ks < 8; ++ks) {
    s16x8 b0, b1;
#pragma unroll
    for (int j = 0; j < 8; ++j) {
      float z = Zt[ks * 16 + hi * 8 + j][rr];
      ushort h0 = f2bf(z);
      float z0f = bf2f(h0);
      ushort h1 = f2bf(z - z0f);
      b0[j] = (short)h0;
      b1[j] = (short)h1;
    }
    B0[ks] = b0; B1[ks] = b1;
  }

  // wave scans its 8 code-subtiles (codes w*256 .. w*256+255, ascending)
  float b1v = 3.4e38f, b2v = 3.4e38f;
  int b1i = 0, b2i = 0;
  const float4* e0p = (const float4*)E0f;
  const float4* e1p = (const float4*)E1f;

  for (int s = 0; s < 8; ++s) {
    const int sg = w * 8 + s;        // global subtile
    f32x16 acc;
#pragma unroll
    for (int i = 0; i < 16; ++i) acc[i] = 0.0f;
    const int base = sg * 512 + lane;
#pragma unroll
    for (int ks = 0; ks < 8; ++ks) {
      F4S8 ua, ub;
      ua.f = e0p[base + ks * 64];
      ub.f = e1p[base + ks * 64];
      acc = __builtin_amdgcn_mfma_f32_32x32x16_bf16(ua.s, B0[ks], acc, 0, 0, 0);
      acc = __builtin_amdgcn_mfma_f32_32x32x16_bf16(ua.s, B1[ks], acc, 0, 0, 0);
      acc = __builtin_amdgcn_mfma_f32_32x32x16_bf16(ub.s, B0[ks], acc, 0, 0, 0);
    }
    // finalize: lane-local codes, ascending -> first-index tie-break
#pragma unroll
    for (int reg = 0; reg < 16; ++reg) {
      int cl = (reg & 3) + 8 * (reg >> 2) + 4 * hi;
      int c = sg * 32 + cl;
      float rv = fmaf(-2.0f, acc[reg], esh[c]);   // zsq-free ranking key
      if (rv < b1v) { b2v = b1v; b2i = b1i; b1v = rv; b1i = c; }
      else if (rv < b2v) { b2v = rv; b2i = c; }
    }
  }

  // merge the two half-lanes (codes interleave -> lexicographic (val, idx))
  float ov1 = __shfl_xor(b1v, 32, 64); int oi1 = __shfl_xor(b1i, 32, 64);
  float ov2 = __shfl_xor(b2v, 32, 64); int oi2 = __shfl_xor(b2i, 32, 64);
  if (ov1 < b1v || (ov1 == b1v && oi1 < b1i)) { b2v = b1v; b2i = b1i; b1v = ov1; b1i = oi1; }
  else if (ov1 < b2v || (ov1 == b2v && oi1 < b2i)) { b2v = ov1; b2i = oi1; }
  if (ov2 < b2v || (ov2 == b2v && oi2 < b2i)) { b2v = ov2; b2i = oi2; }

  if (hi == 0) {
    mv1[w][rr] = b1v; mi1[w][rr] = b1i;
    mv2[w][rr] = b2v; mi2[w][rr] = b2i;
  }
  __syncthreads();

  // final merge across 4 waves + selective exact refine, one thread per row
  if (tid < 32) {
    const int row = tid;
    float fb1 = mv1[0][row]; int fi1 = mi1[0][row];
    float fb2 = mv2[0][row]; int fi2 = mi2[0][row];
#pragma unroll
    for (int q = 1; q < 4; ++q) {
      float v1 = mv1[q][row]; int i1 = mi1[q][row];
      float v2 = mv2[q][row]; int i2 = mi2[q][row];
      if (v1 < fb1 || (v1 == fb1 && i1 < fi1)) {
        fb2 = fb1; fi2 = fi1; fb1 = v1; fi1 = i1;
      } else if (v1 < fb2 || (v1 == fb2 && i1 < fi2)) {
        fb2 = v1; fi2 = i1;
      }
      if (v2 < fb2 || (v2 == fb2 && i2 < fi2)) { fb2 = v2; fi2 = i2; }
    }

    int fi = fi1;
    if (fb2 - fb1 <= 4e-5f) {
      float zsq = 0.0f;
#pragma unroll 4
      for (int d = 0; d < 128; ++d) {
        float z = Zt[d][row];
        zsq = fmaf(z, z, zsq);
      }
      float dot1 = 0.0f, dot2 = 0.0f;
      const float* e1r = E + (size_t)fi1 * DD;
      const float* e2r = E + (size_t)fi2 * DD;
      for (int d = 0; d < 128; ++d) {
        float z = Zt[d][row];
        dot1 = fmaf(z, e1r[d], dot1);
        dot2 = fmaf(z, e2r[d], dot2);
      }
      float k1 = (zsq + esh[fi1]) - 2.0f * dot1;
      float k2 = (zsq + esh[fi2]) - 2.0f * dot2;
      if (k2 < k1 || (k2 == k1 && fi2 < fi1)) fi = fi2;
    }
    idx_out[r0 + row] = fi;
  }
}

// Counting-sort phase 1: per-block histogram of 1024 indices (LDS-local atomics).
__global__ __launch_bounds__(1024) void k_hist(const int* __restrict__ idxs,
                                               int* __restrict__ part_cnt) {
  __shared__ int h[1024];
  const int tid = threadIdx.x;
  const int j = blockIdx.x;      // 32 blocks
  h[tid] = 0;
  __syncthreads();
  int k = idxs[j * 1024 + tid];
  atomicAdd(&h[k], 1);
  __syncthreads();
  part_cnt[j * 1024 + tid] = h[tid];
}

// Counting-sort phase 2 + cluster EMA fused. Wave-shuffle prefix (3 barriers).
__global__ __launch_bounds__(1024) void k_scan(int* __restrict__ part_cnt,
                                               int* __restrict__ code_start,
                                               int* __restrict__ icnt,
                                               float* __restrict__ counts,
                                               const float* __restrict__ cs_in,
                                               float* __restrict__ smooth,
                                               int* __restrict__ ridx,
                                               int* __restrict__ deadf) {
  const int k = threadIdx.x;
  const int lane = k & 63;
  const int wv = k >> 6;         // 16 waves
  int base[32];
  int s = 0;
#pragma unroll
  for (int j = 0; j < 32; ++j) {
    base[j] = s;
    s += part_cnt[j * 1024 + k];
  }
  icnt[k] = s;
  counts[k] = (float)s;

  // inclusive prefix within wave via shfl_up
  int ps = s;
#pragma unroll
  for (int off = 1; off < 64; off <<= 1) {
    int v = __shfl_up(ps, off, 64);
    if (lane >= off) ps += v;
  }
  __shared__ int wtot[16];
  if (lane == 63) wtot[wv] = ps;
  __syncthreads();
  if (k < 16) {
    int v = wtot[k];
#pragma unroll
    for (int off = 1; off < 16; off <<= 1) {
      int u = __shfl_up(v, off, 64);
      if (lane >= off) v += u;
    }
    wtot[k] = v;   // inclusive wave totals prefix
  }
  __syncthreads();
  int wbase = (wv > 0) ? wtot[wv - 1] : 0;
  int excl = (ps + wbase) - s;
  code_start[k] = excl;
#pragma unroll
  for (int j = 0; j < 32; ++j) {
    part_cnt[j * 1024 + k] = excl + base[j];   // becomes part_base
  }

  // ---- fused cluster EMA (was k_cluster) ----
  float c = (float)s;
  float t1 = 0.99f * cs_in[k];
  float t2 = 0.01f * c;
  float nc = t1 + t2;
  bool dead = nc < 0.5f;

  uint32_t bits;
#if THREEFRY_PARTITIONABLE
  {
    uint32_t o0, o1;
    threefry2x32(0u, 42u, 0u, (uint32_t)k, &o0, &o1);
    bits = o0 ^ o1;
  }
#else
  {
    uint32_t o0, o1;
    if (k < 512) { threefry2x32(0u, 42u, (uint32_t)k, (uint32_t)(k + 512), &o0, &o1); bits = o0; }
    else         { threefry2x32(0u, 42u, (uint32_t)(k - 512), (uint32_t)k, &o0, &o1); bits = o1; }
  }
#endif
  int r = (int)(bits & 0x7FFFu);

  float rep = dead ? 0.5f : nc;

  // block-wide sum of rep: wave butterfly + 16 partials + broadcast
  float fs = rep;
#pragma unroll
  for (int off = 32; off > 0; off >>= 1) fs += __shfl_xor(fs, off, 64);
  __shared__ float ftot[16];
  __shared__ float nsh;
  if (lane == 0) ftot[wv] = fs;
  __syncthreads();
  if (k == 0) {
    float n = 0.0f;
#pragma unroll
    for (int i = 0; i < 16; ++i) n += ftot[i];
    nsh = n;
  }
  __syncthreads();
  float n = nsh;

  float sm = ((rep + 1e-5f) / (n + 0.01024f)) * n;
  smooth[k] = sm;
  ridx[k] = r;
  deadf[k] = dead ? 1 : 0;
}

// Counting-sort phase 3: scatter row ids (LDS cursor seeded from part_base).
__global__ __launch_bounds__(1024) void k_scatter(const int* __restrict__ idxs,
                                                  const int* __restrict__ part_base,
                                                  int* __restrict__ rowlist) {
  __shared__ int cur[1024];
  const int tid = threadIdx.x;
  const int j = blockIdx.x;      // 32 blocks
  cur[tid] = part_base[j * 1024 + tid];
  __syncthreads();
  int row = j * 1024 + tid;
  int k = idxs[row];
  int pos = atomicAdd(&cur[k], 1);
  rowlist[pos] = row;
}

// Gather segment sum via rowlist + fused k_emb — 8 rows in flight per block.
__global__ __launch_bounds__(256) void k_wsum2(const float* __restrict__ zflat,
                                               const int* __restrict__ rowlist,
                                               const int* __restrict__ code_start,
                                               const int* __restrict__ icnt,
                                               const float* __restrict__ avg_in,
                                               const float* __restrict__ smooth,
                                               const int* __restrict__ ridx,
                                               const int* __restrict__ deadf,
                                               float* __restrict__ nemb) {
  const int k = blockIdx.x;
  const int tid = threadIdx.x;
  const int g = tid >> 5;        // row-group 0..7
  const int ln = tid & 31;       // lane -> dims ln*4 .. ln*4+3
  __shared__ float red[8][128];

  const int start = code_start[k];
  const int m = icnt[k];
  float a0 = 0.f, a1 = 0.f, a2 = 0.f, a3 = 0.f;
  for (int j = g; j < m; j += 8) {
    int row = rowlist[start + j];
    const float4 v = *(const float4*)(zflat + (size_t)row * DD + ln * 4);
    a0 += v.x; a1 += v.y; a2 += v.z; a3 += v.w;
  }
  red[g][ln * 4 + 0] = a0;
  red[g][ln * 4 + 1] = a1;
  red[g][ln * 4 + 2] = a2;
  red[g][ln * 4 + 3] = a3;
  __syncthreads();
#pragma unroll
  for (int s = 4; s >= 1; s >>= 1) {
    if (g < s) {
      red[g][ln * 4 + 0] += red[g + s][ln * 4 + 0];
      red[g][ln * 4 + 1] += red[g + s][ln * 4 + 1];
      red[g][ln * 4 + 2] += red[g + s][ln * 4 + 2];
      red[g][ln * 4 + 3] += red[g + s][ln * 4 + 3];
    }
    __syncthreads();
  }
  if (g == 0) {
    const int dd = ln * 4;
    float4 av = *(const float4*)(avg_in + (size_t)k * DD + dd);
    float sm = smooth[k];
    float na0 = 0.99f * av.x + 0.01f * red[0][dd + 0];
    float na1 = 0.99f * av.y + 0.01f * red[0][dd + 1];
    float na2 = 0.99f * av.z + 0.01f * red[0][dd + 2];
    float na3 = 0.99f * av.w + 0.01f * red[0][dd + 3];
    if (deadf[k]) {
      int r = ridx[k];
      const float4 zv = *(const float4*)(zflat + (size_t)r * DD + dd);
      na0 = zv.x * 0.5f;   // rvec * RESTART_THRESHOLD
      na1 = zv.y * 0.5f;
      na2 = zv.z * 0.5f;
      na3 = zv.w * 0.5f;
    }
    float4 o;
    o.x = na0 / sm; o.y = na1 / sm; o.z = na2 / sm; o.w = na3 / sm;
    *(float4*)(nemb + (size_t)k * DD + dd) = o;
  }
}

// Kernel 4: tile-structured gather/output. Block = 32 rows (one b, l-tile).
__global__ __launch_bounds__(256) void k_out(const float* __restrict__ Z,
                                             const float* __restrict__ nemb,
                                             const int* __restrict__ idxs,
                                             float* __restrict__ out,
                                             double* __restrict__ lacc) {
  __shared__ float Zt[128][33];   // [d][row]
  __shared__ float Ot[128][33];   // [d][row] output staged
  __shared__ int sidx[32];
  __shared__ float lred[4];

  const int tid = threadIdx.x;
  const int r0 = blockIdx.x * 32;
  const int b = r0 >> 12;
  const int l0 = r0 & (LL - 1);

  // stage Z tile coalesced (128B contiguous per d)
  const float* zsrc = Z + (size_t)b * DD * LL + l0;
#pragma unroll
  for (int p = 0; p < 4; ++p) {
    int f = p * 256 + tid;
    int d = f >> 3;
    int g = f & 7;
    float4 v = *(const float4*)(zsrc + (size_t)d * LL + g * 4);
    Zt[d][g * 4 + 0] = v.x;
    Zt[d][g * 4 + 1] = v.y;
    Zt[d][g * 4 + 2] = v.z;
    Zt[d][g * 4 + 3] = v.w;
  }
  if (tid < 32) sidx[tid] = idxs[r0 + tid];
  __syncthreads();

  // each 32-lane group handles one row per iter: coalesced 512B nemb row reads
  const int grp = tid >> 5;   // 0..7
  const int ln = tid & 31;
  float lsum = 0.0f;
#pragma unroll
  for (int it = 0; it < 4; ++it) {
    int row = it * 8 + grp;
    int fi = sidx[row];
    float4 q4 = *(const float4*)(nemb + (size_t)fi * DD + ln * 4);
    float z0 = Zt[ln * 4 + 0][row];
    float z1 = Zt[ln * 4 + 1][row];
    float z2 = Zt[ln * 4 + 2][row];
    float z3 = Zt[ln * 4 + 3][row];
    float o0 = z0 + (q4.x - z0);   // reference expr tree: z_e + (z_q - z_e)
    float o1 = z1 + (q4.y - z1);
    float o2 = z2 + (q4.z - z2);
    float o3 = z3 + (q4.w - z3);
    Ot[ln * 4 + 0][row] = o0;
    Ot[ln * 4 + 1][row] = o1;
    Ot[ln * 4 + 2][row] = o2;
    Ot[ln * 4 + 3][row] = o3;
    float d0 = z0 - q4.x, d1 = z1 - q4.y, d2 = z2 - q4.z, d3 = z3 - q4.w;
    lsum += d0 * d0 + d1 * d1 + d2 * d2 + d3 * d3;
  }
  __syncthreads();

  // write z_q_st coalesced (128B contiguous per d)
  float* dstz = out + (size_t)b * DD * LL + l0;
#pragma unroll
  for (int p = 0; p < 4; ++p) {
    int f = p * 256 + tid;
    int d = f >> 3;
    int g = f & 7;
    float4 v;
    v.x = Ot[d][g * 4 + 0];
    v.y = Ot[d][g * 4 + 1];
    v.z = Ot[d][g * 4 + 2];
    v.w = Ot[d][g * 4 + 3];
    *(float4*)(dstz + (size_t)d * LL + g * 4) = v;
  }
  // indices_map as floats
  if (tid < 32) out[(size_t)ZTOT + r0 + tid] = (float)sidx[tid];

  // loss partial: wave reduce then one double atomic per block
  for (int off = 32; off > 0; off >>= 1) lsum += __shfl_down(lsum, off, 64);
  if ((tid & 63) == 0) lred[tid >> 6] = lsum;
  __syncthreads();
  if (tid == 0) {
    float tot = (lred[0] + lred[1]) + (lred[2] + lred[3]);
    atomicAdd(lacc, (double)tot);
  }
}

// Kernel 5: final loss scalars
__global__ void k_fin(const double* __restrict__ lacc, float* __restrict__ out) {
  double S = lacc[0];
  float cb = (float)(S / (double)ZTOT);
  float bc = 0.25f * cb;
  float vq = cb + bc;
  float* o = out + (size_t)ZTOT + NN;
  o[0] = vq;
  o[1] = cb;
  o[2] = bc;
}

extern "C" void kernel_launch(void* const* d_in, const int* in_sizes, int n_in,
                              void* d_out, int out_size, void* d_ws, size_t ws_size,
                              hipStream_t stream) {
  const float* Z  = (const float*)d_in[0];   // z_e        (8,128,4096)
  const float* E  = (const float*)d_in[1];   // embedding  (1024,128)
  const float* CS = (const float*)d_in[2];   // cluster_size (1024,)
  const float* EA = (const float*)d_in[3];   // embedding_avg (1024,128)
  float* out = (float*)d_out;
  float* ws = (float*)d_ws;

  float* counts = ws;                        // 1024
  float* esq    = ws + 1024;                 // 1024
  float* smooth = ws + 2048;                 // 1024
  int*   ridx   = (int*)(ws + 3072);         // 1024
  int*   deadf  = (int*)(ws + 4096);         // 1024
  float* nemb   = ws + 8192 + 131072;        // 131072 floats (512 KB)
  int*   idxs   = (int*)(ws + 270336);       // 32768
  double* lacc  = (double*)(ws + 303104);    // 8B aligned

  int* rowlist    = (int*)(ws + 303360);     // 32768 ints
  int* code_start = (int*)(ws + 336128);     // 1024 ints
  int* icnt       = (int*)(ws + 337152);     // 1024 ints

  // bf16-split E fragment buffers reuse the nemb slot: consumed by k_dist;
  // part_cnt then reuses the same slot; k_wsum2 finally writes nemb.
  ushort* E0f = (ushort*)nemb;
  ushort* E1f = (ushort*)(nemb + 65536);
  int* part_cnt = (int*)nemb;

  // zflat (N,D) = 16.8 MB parked in d_out[0..ZTOT): written by k_dist (fused
  // transpose), consumed by k_wsum2, overwritten by k_out (stream-ordered).
  float* zflat = out;

  k_prep<<<KC, DD, 0, stream>>>(E, esq, lacc, E0f, E1f);
  k_dist<<<NN / 32, 256, 0, stream>>>(Z, E, E0f, E1f, esq, idxs, zflat);
  k_hist<<<32, 1024, 0, stream>>>(idxs, part_cnt);
  k_scan<<<1, 1024, 0, stream>>>(part_cnt, code_start, icnt, counts,
                                 CS, smooth, ridx, deadf);
  k_scatter<<<32, 1024, 0, stream>>>(idxs, part_cnt, rowlist);
  k_wsum2<<<KC, 256, 0, stream>>>(zflat, rowlist, code_start, icnt,
                                  EA, smooth, ridx, deadf, nemb);
  k_out<<<NN / 32, 256, 0, stream>>>(Z, nemb, idxs, out, lacc);
  k_fin<<<1, 1, 0, stream>>>(lacc, out);
}